// Round 1
// 1235.767 us; speedup vs baseline: 1.3223x; 1.3223x over previous
//
#include <hip/hip_runtime.h>
#include <hip/hip_bf16.h>
#include <stdint.h>

#define K_DIM 4096
#define BM 256
#define BN 256
#define BK 32
#define NT (K_DIM / BK)   // 128 K-tiles

typedef __bf16 bf16_t;
typedef __bf16 bf16x8 __attribute__((ext_vector_type(8)));
typedef __bf16 bf16x4 __attribute__((ext_vector_type(4)));
typedef float f32x4 __attribute__((ext_vector_type(4)));

// async global->LDS, 16B per lane. LDS dest = wave-uniform base + lane*16B.
__device__ inline void async16(const bf16_t* g, bf16_t* l) {
  __builtin_amdgcn_global_load_lds(
      (const __attribute__((address_space(1))) void*)g,
      (__attribute__((address_space(3))) void*)l, 16, 0, 0);
}

// ---------------- preprocessing (unchanged, ~7% of runtime) ----------------

__device__ inline float wave_block_max(float v, float* red) {
  #pragma unroll
  for (int off = 32; off > 0; off >>= 1)
    v = fmaxf(v, __shfl_xor(v, off, 64));
  int lane = threadIdx.x & 63, wid = threadIdx.x >> 6;
  if (lane == 0) red[wid] = v;
  __syncthreads();
  return fmaxf(fmaxf(red[0], red[1]), fmaxf(red[2], red[3]));
}

__global__ void colmask_kernel(const float* __restrict__ x,
                               const float* __restrict__ sigma,
                               int* __restrict__ mask, long total4) {
  long i = (long)blockIdx.x * blockDim.x + threadIdx.x;
  if (i >= total4) return;
  float sig = sigma[0];
  float4 v = ((const float4*)x)[i];
  int k = (int)((i * 4) % K_DIM);
  if (fabsf(v.x) > sig) mask[k + 0] = 1;
  if (fabsf(v.y) > sig) mask[k + 1] = 1;
  if (fabsf(v.z) > sig) mask[k + 2] = 1;
  if (fabsf(v.w) > sig) mask[k + 3] = 1;
}

__global__ __launch_bounds__(256) void fused_w_kernel(
    const float* __restrict__ W, float* __restrict__ scale,
    bf16_t* __restrict__ Wq) {
  __shared__ float red[4];
  int n = blockIdx.x;
  const float4* row = (const float4*)(W + (size_t)n * K_DIM);
  float4 v[4];
  float amax = 0.f;
  #pragma unroll
  for (int j = 0; j < 4; j++) {
    v[j] = row[threadIdx.x + j * 256];
    amax = fmaxf(amax, fmaxf(fmaxf(fabsf(v[j].x), fabsf(v[j].y)),
                             fmaxf(fabsf(v[j].z), fabsf(v[j].w))));
  }
  float mx = wave_block_max(amax, red);
  float s = mx * (1.0f / 64.0f);
  if (threadIdx.x == 0) scale[n] = s;
  float is = (s > 0.f) ? 1.0f / s : 0.f;
  bf16_t* orow = Wq + (size_t)n * K_DIM;
  #pragma unroll
  for (int j = 0; j < 4; j++) {
    bf16x4 q;
    q[0] = (bf16_t)rintf(v[j].x * is);
    q[1] = (bf16_t)rintf(v[j].y * is);
    q[2] = (bf16_t)rintf(v[j].z * is);
    q[3] = (bf16_t)rintf(v[j].w * is);
    *(bf16x4*)(orow + (size_t)(threadIdx.x + j * 256) * 4) = q;
  }
}

__global__ __launch_bounds__(256) void fused_x_kernel(
    const float* __restrict__ x, const int* __restrict__ mask,
    float* __restrict__ xs, bf16_t* __restrict__ Aq) {
  __shared__ float red[4];
  int m = blockIdx.x;
  const float4* row = (const float4*)(x + (size_t)m * K_DIM);
  const int4* mk = (const int4*)mask;
  float4 v[4];
  int4 b[4];
  float amax = 0.f;
  #pragma unroll
  for (int j = 0; j < 4; j++) {
    v[j] = row[threadIdx.x + j * 256];
    b[j] = mk[threadIdx.x + j * 256];
    if (!b[j].x) amax = fmaxf(amax, fabsf(v[j].x));
    if (!b[j].y) amax = fmaxf(amax, fabsf(v[j].y));
    if (!b[j].z) amax = fmaxf(amax, fabsf(v[j].z));
    if (!b[j].w) amax = fmaxf(amax, fabsf(v[j].w));
  }
  float mx = wave_block_max(amax, red);
  float s = fmaxf(mx * (1.0f / 127.0f), 1e-8f);
  if (threadIdx.x == 0) xs[m] = s;
  float iv = 1.0f / s;
  bf16_t* orow = Aq + (size_t)m * K_DIM;
  #pragma unroll
  for (int j = 0; j < 4; j++) {
    float f0 = v[j].x * iv, f1 = v[j].y * iv, f2 = v[j].z * iv, f3 = v[j].w * iv;
    bf16x4 q;
    q[0] = (bf16_t)(b[j].x ? f0 : rintf(f0));
    q[1] = (bf16_t)(b[j].y ? f1 : rintf(f1));
    q[2] = (bf16_t)(b[j].z ? f2 : rintf(f2));
    q[3] = (bf16_t)(b[j].w ? f3 : rintf(f3));
    *(bf16x4*)(orow + (size_t)(threadIdx.x + j * 256) * 4) = q;
  }
}

// ---------------- GEMM: 256x256 tile, 8 waves, 4-slot LDS ring, phased ----------------
// out[m,n] = xs[m]*sc[n] * sum_k A[m,k]*B[n,k]
//
// LDS slot s (32 KiB): A[256][32] at s*16384 elems, B[256][32] at +8192 elems.
// Logical (row,k) stored at byte row*64 + ((k>>3) ^ ((row>>1)&3))*16 + (k&7)*2.
//   -> ds_read_b128 fragment loads: 16-lane groups hit all 8 bank-groups 2x (free).
//   -> global_load_lds dest stays LINEAR; the global SOURCE column is pre-swizzled
//      with the same involution (rule: both-sides-or-neither).
// Pipeline: prefetch distance 3 tiles; per-tile checkpoint = vmcnt(8)+barrier
// (8 loads = 2 tiles in flight), never vmcnt(0) until the drain tail.

__global__ __launch_bounds__(512, 2) void gemm_kernel(
    const bf16_t* __restrict__ A, const bf16_t* __restrict__ B,
    const float* __restrict__ xs, const float* __restrict__ sc,
    float* __restrict__ out, int M, int N) {
  __shared__ __align__(16) bf16_t lds[4 * 16384];  // 128 KiB

  const int tid  = threadIdx.x;
  const int lane = tid & 63;
  const int wave = tid >> 6;               // 0..7
  const int wmBase = (wave >> 2) * 128;    // wave's M offset (2 rows of waves)
  const int wnBase = (wave & 3) * 64;      // wave's N offset (4 cols of waves)
  const int l15  = lane & 15;
  const int quad = lane >> 4;
  const int swz8 = (quad ^ ((l15 >> 1) & 3)) * 8;  // swizzled k-slot, in elems

  // XCD-aware bijective tile mapping: nwg = (M/256)*(N/256) = 32*43 = 1376 (%8==0).
  // XCD c owns tm in [4c,4c+4); tm fastest in groups of 4 -> B-tile L2 reuse x4.
  const int ntn = N / BN;
  const int nwg = (M / BM) * ntn;
  int bid = blockIdx.x;
  int lid = (bid & 7) * (nwg >> 3) + (bid >> 3);
  const int g4 = ntn * 4;
  const int tm = (lid / g4) * 4 + (lid & 3);
  const int tn = (lid % g4) >> 2;
  const int bm = tm * BM;
  const int bn = tn * BN;

  // staging: thread covers 16B; chunk j = rows j*128..j*128+127
  // stored slot = lane&3; logical k-slot = (lane&3) ^ ((row>>1)&3) = (lane&3)^((lane>>3)&3)
  const int srow = wave * 16 + (lane >> 2);
  const int scol = ((lane & 3) ^ ((lane >> 3) & 3)) * 8;
  const bf16_t* gA = A + (size_t)(bm + srow) * K_DIM + scol;
  const bf16_t* gB = B + (size_t)(bn + srow) * K_DIM + scol;
  bf16_t* ldsA = lds + wave * 512;          // + slot*16384 + chunk*4096
  bf16_t* ldsB = lds + 8192 + wave * 512;

  auto stageA = [&](int t) {
    const bf16_t* g = gA + (size_t)t * BK;
    bf16_t* d = ldsA + (t & 3) * 16384;
    async16(g, d);
    async16(g + (size_t)128 * K_DIM, d + 4096);
  };
  auto stageB = [&](int t) {
    const bf16_t* g = gB + (size_t)t * BK;
    bf16_t* d = ldsB + (t & 3) * 16384;
    async16(g, d);
    async16(g + (size_t)128 * K_DIM, d + 4096);
  };

  f32x4 acc[8][4];
  #pragma unroll
  for (int i = 0; i < 8; ++i)
    #pragma unroll
    for (int j = 0; j < 4; ++j)
      #pragma unroll
      for (int e = 0; e < 4; ++e) acc[i][j][e] = 0.f;

  // prologue: tiles 0,1,2 in flight (12 loads); wait tile 0 (oldest 4)
  stageA(0); stageB(0); stageA(1); stageB(1); stageA(2); stageB(2);
  asm volatile("s_waitcnt vmcnt(8)" ::: "memory");
  __builtin_amdgcn_s_barrier();

  for (int t = 0; t < NT; ++t) {
    const bf16_t* Asl = lds + (t & 3) * 16384;
    const bf16_t* Bsl = Asl + 8192;
    bf16x8 af[4], bf[4];

    // ---- phase A: M-frags 0-3, all 4 N-frags ----
    #pragma unroll
    for (int i = 0; i < 4; ++i)
      af[i] = *(const bf16x8*)(Asl + (wmBase + i * 16 + l15) * 32 + swz8);
    #pragma unroll
    for (int j = 0; j < 4; ++j)
      bf[j] = *(const bf16x8*)(Bsl + (wnBase + j * 16 + l15) * 32 + swz8);
    if (t + 3 < NT) stageA(t + 3);   // slot (t+3)&3 == (t-1)&3: reads done last tile
    __builtin_amdgcn_s_barrier();
    asm volatile("s_waitcnt lgkmcnt(0)" ::: "memory");
    __builtin_amdgcn_sched_barrier(0);
    __builtin_amdgcn_s_setprio(1);
    #pragma unroll
    for (int i = 0; i < 4; ++i)
      #pragma unroll
      for (int j = 0; j < 4; ++j)
        acc[i][j] = __builtin_amdgcn_mfma_f32_16x16x32_bf16(af[i], bf[j],
                                                            acc[i][j], 0, 0, 0);
    __builtin_amdgcn_s_setprio(0);
    __builtin_amdgcn_sched_barrier(0);
    __builtin_amdgcn_s_barrier();

    // ---- phase B: M-frags 4-7 (bf reused in registers) ----
    #pragma unroll
    for (int i = 0; i < 4; ++i)
      af[i] = *(const bf16x8*)(Asl + (wmBase + 64 + i * 16 + l15) * 32 + swz8);
    if (t + 3 < NT) stageB(t + 3);
    __builtin_amdgcn_s_barrier();
    asm volatile("s_waitcnt lgkmcnt(0)" ::: "memory");
    __builtin_amdgcn_sched_barrier(0);
    __builtin_amdgcn_s_setprio(1);
    #pragma unroll
    for (int i = 0; i < 4; ++i)
      #pragma unroll
      for (int j = 0; j < 4; ++j)
        acc[4 + i][j] = __builtin_amdgcn_mfma_f32_16x16x32_bf16(af[i], bf[j],
                                                                acc[4 + i][j], 0, 0, 0);
    __builtin_amdgcn_s_setprio(0);
    __builtin_amdgcn_sched_barrier(0);

    // ---- checkpoint: ensure tile t+1 landed; keep 2 tiles (8 loads) in flight ----
    if (t + 1 < NT) {
      int rem = NT - 1 - t;
      if (rem >= 3)      asm volatile("s_waitcnt vmcnt(8)" ::: "memory");
      else if (rem == 2) asm volatile("s_waitcnt vmcnt(4)" ::: "memory");
      else               asm volatile("s_waitcnt vmcnt(0)" ::: "memory");
      __builtin_amdgcn_s_barrier();
    }
  }

  // epilogue: C/D layout col=lane&15, row=quad*4+reg
  float scv[4];
  #pragma unroll
  for (int tj = 0; tj < 4; ++tj) scv[tj] = sc[bn + wnBase + tj * 16 + l15];
  #pragma unroll
  for (int mi = 0; mi < 8; ++mi) {
    #pragma unroll
    for (int i = 0; i < 4; ++i) {
      int row = bm + wmBase + mi * 16 + quad * 4 + i;
      float s_row = xs[row];
      float* orow = out + (size_t)row * N + bn + wnBase + l15;
      #pragma unroll
      for (int tj = 0; tj < 4; ++tj)
        orow[tj * 16] = acc[mi][tj][i] * s_row * scv[tj];
    }
  }
}

// ---------------- launch ----------------

extern "C" void kernel_launch(void* const* d_in, const int* in_sizes, int n_in,
                              void* d_out, int out_size, void* d_ws, size_t ws_size,
                              hipStream_t stream) {
  const float* x = (const float*)d_in[0];
  const float* W = (const float*)d_in[1];
  const float* sigma = (const float*)d_in[2];
  float* out = (float*)d_out;

  const int K = K_DIM;
  const int M = in_sizes[0] / K;  // 8192
  const int N = in_sizes[1] / K;  // 11008

  char* ws = (char*)d_ws;
  size_t off = 0;
  auto alloc = [&](size_t bytes) -> void* {
    void* p = ws + off;
    off += (bytes + 255) & ~(size_t)255;
    return p;
  };
  float* scale_col = (float*)alloc((size_t)N * 4);
  int*   mask      = (int*)alloc((size_t)K * 4);
  float* xs        = (float*)alloc((size_t)M * 4);
  bf16_t* Wq       = (bf16_t*)alloc((size_t)N * K * 2);
  bf16_t* Aq       = (bf16_t*)alloc((size_t)M * K * 2);

  hipMemsetAsync(mask, 0, (size_t)K * sizeof(int), stream);

  long total4 = (long)M * K / 4;
  colmask_kernel<<<(int)((total4 + 255) / 256), 256, 0, stream>>>(x, sigma, mask, total4);

  fused_w_kernel<<<N, 256, 0, stream>>>(W, scale_col, Wq);
  fused_x_kernel<<<M, 256, 0, stream>>>(x, mask, xs, Aq);

  dim3 grid((M / BM) * (N / BN));  // 1376 blocks, XCD-swizzled in-kernel
  gemm_kernel<<<grid, 512, 0, stream>>>(Aq, Wq, xs, scale_col, out, M, N);
}

// Round 2
// 1202.311 us; speedup vs baseline: 1.3591x; 1.0278x over previous
//
#include <hip/hip_runtime.h>
#include <hip/hip_bf16.h>
#include <stdint.h>

#define K_DIM 4096
#define BM 256
#define BN 256
#define BK 32
#define NT (K_DIM / BK)   // 128 K-tiles

typedef __bf16 bf16_t;
typedef __bf16 bf16x8 __attribute__((ext_vector_type(8)));
typedef __bf16 bf16x4 __attribute__((ext_vector_type(4)));
typedef float f32x4 __attribute__((ext_vector_type(4)));

// async global->LDS, 16B per lane. LDS dest = wave-uniform base + lane*16B.
__device__ inline void async16(const bf16_t* g, bf16_t* l) {
  __builtin_amdgcn_global_load_lds(
      (const __attribute__((address_space(1))) void*)g,
      (__attribute__((address_space(3))) void*)l, 16, 0, 0);
}

// ---------------- preprocessing ----------------

__device__ inline float wave_block_max(float v, float* red) {
  #pragma unroll
  for (int off = 32; off > 0; off >>= 1)
    v = fmaxf(v, __shfl_xor(v, off, 64));
  int lane = threadIdx.x & 63, wid = threadIdx.x >> 6;
  if (lane == 0) red[wid] = v;
  __syncthreads();
  return fmaxf(fmaxf(red[0], red[1]), fmaxf(red[2], red[3]));
}

// grid-stride: 131k trivial blocks -> 4096 blocks (block-turnaround was the cost)
__global__ __launch_bounds__(256) void colmask_kernel(
    const float* __restrict__ x, const float* __restrict__ sigma,
    int* __restrict__ mask, long total4) {
  float sig = sigma[0];
  long stride = (long)gridDim.x * blockDim.x;
  for (long i = (long)blockIdx.x * blockDim.x + threadIdx.x; i < total4;
       i += stride) {
    float4 v = ((const float4*)x)[i];
    int k = (int)((i * 4) & (K_DIM - 1));
    if (fabsf(v.x) > sig) mask[k + 0] = 1;
    if (fabsf(v.y) > sig) mask[k + 1] = 1;
    if (fabsf(v.z) > sig) mask[k + 2] = 1;
    if (fabsf(v.w) > sig) mask[k + 3] = 1;
  }
}

__global__ __launch_bounds__(256) void fused_w_kernel(
    const float* __restrict__ W, float* __restrict__ scale,
    bf16_t* __restrict__ Wq) {
  __shared__ float red[4];
  int n = blockIdx.x;
  const float4* row = (const float4*)(W + (size_t)n * K_DIM);
  float4 v[4];
  float amax = 0.f;
  #pragma unroll
  for (int j = 0; j < 4; j++) {
    v[j] = row[threadIdx.x + j * 256];
    amax = fmaxf(amax, fmaxf(fmaxf(fabsf(v[j].x), fabsf(v[j].y)),
                             fmaxf(fabsf(v[j].z), fabsf(v[j].w))));
  }
  float mx = wave_block_max(amax, red);
  float s = mx * (1.0f / 64.0f);
  if (threadIdx.x == 0) scale[n] = s;
  float is = (s > 0.f) ? 1.0f / s : 0.f;
  bf16_t* orow = Wq + (size_t)n * K_DIM;
  #pragma unroll
  for (int j = 0; j < 4; j++) {
    bf16x4 q;
    q[0] = (bf16_t)rintf(v[j].x * is);
    q[1] = (bf16_t)rintf(v[j].y * is);
    q[2] = (bf16_t)rintf(v[j].z * is);
    q[3] = (bf16_t)rintf(v[j].w * is);
    *(bf16x4*)(orow + (size_t)(threadIdx.x + j * 256) * 4) = q;
  }
}

__global__ __launch_bounds__(256) void fused_x_kernel(
    const float* __restrict__ x, const int* __restrict__ mask,
    float* __restrict__ xs, bf16_t* __restrict__ Aq) {
  __shared__ float red[4];
  int m = blockIdx.x;
  const float4* row = (const float4*)(x + (size_t)m * K_DIM);
  const int4* mk = (const int4*)mask;
  float4 v[4];
  int4 b[4];
  float amax = 0.f;
  #pragma unroll
  for (int j = 0; j < 4; j++) {
    v[j] = row[threadIdx.x + j * 256];
    b[j] = mk[threadIdx.x + j * 256];
    if (!b[j].x) amax = fmaxf(amax, fabsf(v[j].x));
    if (!b[j].y) amax = fmaxf(amax, fabsf(v[j].y));
    if (!b[j].z) amax = fmaxf(amax, fabsf(v[j].z));
    if (!b[j].w) amax = fmaxf(amax, fabsf(v[j].w));
  }
  float mx = wave_block_max(amax, red);
  float s = fmaxf(mx * (1.0f / 127.0f), 1e-8f);
  if (threadIdx.x == 0) xs[m] = s;
  float iv = 1.0f / s;
  bf16_t* orow = Aq + (size_t)m * K_DIM;
  #pragma unroll
  for (int j = 0; j < 4; j++) {
    float f0 = v[j].x * iv, f1 = v[j].y * iv, f2 = v[j].z * iv, f3 = v[j].w * iv;
    bf16x4 q;
    q[0] = (bf16_t)(b[j].x ? f0 : rintf(f0));
    q[1] = (bf16_t)(b[j].y ? f1 : rintf(f1));
    q[2] = (bf16_t)(b[j].z ? f2 : rintf(f2));
    q[3] = (bf16_t)(b[j].w ? f3 : rintf(f3));
    *(bf16x4*)(orow + (size_t)(threadIdx.x + j * 256) * 4) = q;
  }
}

// ---------------- GEMM: 256x256 tile, 8 waves, 4-slot LDS ring ----------------
// out[m,n] = xs[m]*sc[n] * sum_k A[m,k]*B[n,k]
//
// LDS slot s (32 KiB): A[256][32] at s*16384 elems, B[256][32] at +8192 elems.
// Logical (row,k) stored at byte row*64 + ((k>>3) ^ ((row>>1)&3))*16 + (k&7)*2.
//   -> ds_read_b128 fragment loads: 16-lane groups hit all 8 bank-groups 2x (free;
//      verified: SQ_LDS_BANK_CONFLICT == 0).
//   -> global_load_lds dest stays LINEAR; global SOURCE column pre-swizzled with
//      the same involution (both-sides-or-neither rule).
//
// Schedule v2: ONE barrier per K-tile. All 12 ds_reads (afA0-3, bf0-3, afB0-3)
// issued at tile top; hipcc inserts counted lgkmcnt so MFMA-A starts after the
// first 8 and afB completes UNDER MFMA-A. Correctness needs only the per-tile
// checkpoint: vmcnt ladder (8/4/0, never 0 until drain tail) + s_barrier
// guarantees slot t+1 landed and all reads of the slot being overwritten are
// long drained (each wave's lgkm hits 0 inside the tile body before the barrier).

__global__ __launch_bounds__(512, 2) void gemm_kernel(
    const bf16_t* __restrict__ A, const bf16_t* __restrict__ B,
    const float* __restrict__ xs, const float* __restrict__ sc,
    float* __restrict__ out, int M, int N) {
  __shared__ __align__(16) bf16_t lds[4 * 16384];  // 128 KiB

  const int tid  = threadIdx.x;
  const int lane = tid & 63;
  const int wave = tid >> 6;               // 0..7
  const int wmBase = (wave >> 2) * 128;    // wave's M offset
  const int wnBase = (wave & 3) * 64;      // wave's N offset
  const int l15  = lane & 15;
  const int quad = lane >> 4;
  const int swz8 = (quad ^ ((l15 >> 1) & 3)) * 8;  // swizzled k-slot, elems

  // XCD-aware bijective tile mapping: nwg = 32*43 = 1376 (%8==0).
  const int ntn = N / BN;
  const int nwg = (M / BM) * ntn;
  int bid = blockIdx.x;
  int lid = (bid & 7) * (nwg >> 3) + (bid >> 3);
  const int g4 = ntn * 4;
  const int tm = (lid / g4) * 4 + (lid & 3);
  const int tn = (lid % g4) >> 2;
  const int bm = tm * BM;
  const int bn = tn * BN;

  // staging: stored slot = lane&3; logical k-slot = (lane&3)^((lane>>3)&3)
  const int srow = wave * 16 + (lane >> 2);
  const int scol = ((lane & 3) ^ ((lane >> 3) & 3)) * 8;
  const bf16_t* gA = A + (size_t)(bm + srow) * K_DIM + scol;
  const bf16_t* gB = B + (size_t)(bn + srow) * K_DIM + scol;
  bf16_t* ldsA = lds + wave * 512;
  bf16_t* ldsB = lds + 8192 + wave * 512;

  auto stageA = [&](int t) {
    const bf16_t* g = gA + (size_t)t * BK;
    bf16_t* d = ldsA + (t & 3) * 16384;
    async16(g, d);
    async16(g + (size_t)128 * K_DIM, d + 4096);
  };
  auto stageB = [&](int t) {
    const bf16_t* g = gB + (size_t)t * BK;
    bf16_t* d = ldsB + (t & 3) * 16384;
    async16(g, d);
    async16(g + (size_t)128 * K_DIM, d + 4096);
  };

  f32x4 acc[8][4];
  #pragma unroll
  for (int i = 0; i < 8; ++i)
    #pragma unroll
    for (int j = 0; j < 4; ++j)
      #pragma unroll
      for (int e = 0; e < 4; ++e) acc[i][j][e] = 0.f;

  // prologue: tiles 0,1,2 in flight (12 loads); wait tile 0 (oldest 4)
  stageA(0); stageB(0); stageA(1); stageB(1); stageA(2); stageB(2);
  asm volatile("s_waitcnt vmcnt(8)" ::: "memory");
  __builtin_amdgcn_s_barrier();

  for (int t = 0; t < NT; ++t) {
    const bf16_t* Asl = lds + (t & 3) * 16384;
    const bf16_t* Bsl = Asl + 8192;
    bf16x8 afA[4], bfr[4], afB[4];

    // all 12 reads up front, phase-A's 8 first (hipcc emits counted lgkmcnt)
    #pragma unroll
    for (int i = 0; i < 4; ++i)
      afA[i] = *(const bf16x8*)(Asl + (wmBase + i * 16 + l15) * 32 + swz8);
    #pragma unroll
    for (int j = 0; j < 4; ++j)
      bfr[j] = *(const bf16x8*)(Bsl + (wnBase + j * 16 + l15) * 32 + swz8);
    #pragma unroll
    for (int i = 0; i < 4; ++i)
      afB[i] = *(const bf16x8*)(Asl + (wmBase + 64 + i * 16 + l15) * 32 + swz8);

    // prefetch tile t+3 -> slot (t-1)&3 (reads of it drained before last barrier)
    if (t + 3 < NT) { stageA(t + 3); stageB(t + 3); }
    __builtin_amdgcn_sched_barrier(0);

    __builtin_amdgcn_s_setprio(1);
    #pragma unroll
    for (int i = 0; i < 4; ++i)
      #pragma unroll
      for (int j = 0; j < 4; ++j)
        acc[i][j] = __builtin_amdgcn_mfma_f32_16x16x32_bf16(afA[i], bfr[j],
                                                            acc[i][j], 0, 0, 0);
    __builtin_amdgcn_s_setprio(0);
    __builtin_amdgcn_sched_barrier(0);

    __builtin_amdgcn_s_setprio(1);
    #pragma unroll
    for (int i = 0; i < 4; ++i)
      #pragma unroll
      for (int j = 0; j < 4; ++j)
        acc[4 + i][j] = __builtin_amdgcn_mfma_f32_16x16x32_bf16(afB[i], bfr[j],
                                                                acc[4 + i][j], 0, 0, 0);
    __builtin_amdgcn_s_setprio(0);
    __builtin_amdgcn_sched_barrier(0);

    // checkpoint: ensure tile t+1 landed; keep up to 2 tiles (8 loads) in flight
    if (t + 1 < NT) {
      int rem = NT - 1 - t;
      if (rem >= 3)      asm volatile("s_waitcnt vmcnt(8)" ::: "memory");
      else if (rem == 2) asm volatile("s_waitcnt vmcnt(4)" ::: "memory");
      else               asm volatile("s_waitcnt vmcnt(0)" ::: "memory");
      __builtin_amdgcn_s_barrier();
    }
  }

  // epilogue: C/D layout col=lane&15, row=quad*4+reg
  float scv[4];
  #pragma unroll
  for (int tj = 0; tj < 4; ++tj) scv[tj] = sc[bn + wnBase + tj * 16 + l15];
  #pragma unroll
  for (int mi = 0; mi < 8; ++mi) {
    #pragma unroll
    for (int i = 0; i < 4; ++i) {
      int row = bm + wmBase + mi * 16 + quad * 4 + i;
      float s_row = xs[row];
      float* orow = out + (size_t)row * N + bn + wnBase + l15;
      #pragma unroll
      for (int tj = 0; tj < 4; ++tj)
        orow[tj * 16] = acc[mi][tj][i] * s_row * scv[tj];
    }
  }
}

// ---------------- launch ----------------

extern "C" void kernel_launch(void* const* d_in, const int* in_sizes, int n_in,
                              void* d_out, int out_size, void* d_ws, size_t ws_size,
                              hipStream_t stream) {
  const float* x = (const float*)d_in[0];
  const float* W = (const float*)d_in[1];
  const float* sigma = (const float*)d_in[2];
  float* out = (float*)d_out;

  const int K = K_DIM;
  const int M = in_sizes[0] / K;  // 8192
  const int N = in_sizes[1] / K;  // 11008

  char* ws = (char*)d_ws;
  size_t off = 0;
  auto alloc = [&](size_t bytes) -> void* {
    void* p = ws + off;
    off += (bytes + 255) & ~(size_t)255;
    return p;
  };
  float* scale_col = (float*)alloc((size_t)N * 4);
  int*   mask      = (int*)alloc((size_t)K * 4);
  float* xs        = (float*)alloc((size_t)M * 4);
  bf16_t* Wq       = (bf16_t*)alloc((size_t)N * K * 2);
  bf16_t* Aq       = (bf16_t*)alloc((size_t)M * K * 2);

  hipMemsetAsync(mask, 0, (size_t)K * sizeof(int), stream);

  long total4 = (long)M * K / 4;
  colmask_kernel<<<4096, 256, 0, stream>>>(x, sigma, mask, total4);

  fused_w_kernel<<<N, 256, 0, stream>>>(W, scale_col, Wq);
  fused_x_kernel<<<M, 256, 0, stream>>>(x, mask, xs, Aq);

  dim3 grid((M / BM) * (N / BN));  // 1376 blocks, XCD-swizzled in-kernel
  gemm_kernel<<<grid, 512, 0, stream>>>(Aq, Wq, xs, scale_col, out, M, N);
}

// Round 3
// 1154.396 us; speedup vs baseline: 1.4155x; 1.0415x over previous
//
#include <hip/hip_runtime.h>
#include <hip/hip_bf16.h>
#include <stdint.h>

#define K_DIM 4096
#define BM 256
#define BN 256
#define BK 32
#define NT (K_DIM / BK)   // 128 K-tiles

typedef __bf16 bf16_t;
typedef __bf16 bf16x8 __attribute__((ext_vector_type(8)));
typedef __bf16 bf16x4 __attribute__((ext_vector_type(4)));
typedef float f32x4 __attribute__((ext_vector_type(4)));

// async global->LDS, 16B per lane. LDS dest = wave-uniform base + lane*16B.
__device__ inline void async16(const bf16_t* g, bf16_t* l) {
  __builtin_amdgcn_global_load_lds(
      (const __attribute__((address_space(1))) void*)g,
      (__attribute__((address_space(3))) void*)l, 16, 0, 0);
}

// ---------------- preprocessing ----------------

__device__ inline float wave_block_max(float v, float* red) {
  #pragma unroll
  for (int off = 32; off > 0; off >>= 1)
    v = fmaxf(v, __shfl_xor(v, off, 64));
  int lane = threadIdx.x & 63, wid = threadIdx.x >> 6;
  if (lane == 0) red[wid] = v;
  __syncthreads();
  return fmaxf(fmaxf(red[0], red[1]), fmaxf(red[2], red[3]));
}

__global__ __launch_bounds__(256) void colmask_kernel(
    const float* __restrict__ x, const float* __restrict__ sigma,
    int* __restrict__ mask, long total4) {
  float sig = sigma[0];
  long stride = (long)gridDim.x * blockDim.x;
  for (long i = (long)blockIdx.x * blockDim.x + threadIdx.x; i < total4;
       i += stride) {
    float4 v = ((const float4*)x)[i];
    int k = (int)((i * 4) & (K_DIM - 1));
    if (fabsf(v.x) > sig) mask[k + 0] = 1;
    if (fabsf(v.y) > sig) mask[k + 1] = 1;
    if (fabsf(v.z) > sig) mask[k + 2] = 1;
    if (fabsf(v.w) > sig) mask[k + 3] = 1;
  }
}

__global__ __launch_bounds__(256) void fused_w_kernel(
    const float* __restrict__ W, float* __restrict__ scale,
    bf16_t* __restrict__ Wq) {
  __shared__ float red[4];
  int n = blockIdx.x;
  const float4* row = (const float4*)(W + (size_t)n * K_DIM);
  float4 v[4];
  float amax = 0.f;
  #pragma unroll
  for (int j = 0; j < 4; j++) {
    v[j] = row[threadIdx.x + j * 256];
    amax = fmaxf(amax, fmaxf(fmaxf(fabsf(v[j].x), fabsf(v[j].y)),
                             fmaxf(fabsf(v[j].z), fabsf(v[j].w))));
  }
  float mx = wave_block_max(amax, red);
  float s = mx * (1.0f / 64.0f);
  if (threadIdx.x == 0) scale[n] = s;
  float is = (s > 0.f) ? 1.0f / s : 0.f;
  bf16_t* orow = Wq + (size_t)n * K_DIM;
  #pragma unroll
  for (int j = 0; j < 4; j++) {
    bf16x4 q;
    q[0] = (bf16_t)rintf(v[j].x * is);
    q[1] = (bf16_t)rintf(v[j].y * is);
    q[2] = (bf16_t)rintf(v[j].z * is);
    q[3] = (bf16_t)rintf(v[j].w * is);
    *(bf16x4*)(orow + (size_t)(threadIdx.x + j * 256) * 4) = q;
  }
}

__global__ __launch_bounds__(256) void fused_x_kernel(
    const float* __restrict__ x, const int* __restrict__ mask,
    float* __restrict__ xs, bf16_t* __restrict__ Aq) {
  __shared__ float red[4];
  int m = blockIdx.x;
  const float4* row = (const float4*)(x + (size_t)m * K_DIM);
  const int4* mk = (const int4*)mask;
  float4 v[4];
  int4 b[4];
  float amax = 0.f;
  #pragma unroll
  for (int j = 0; j < 4; j++) {
    v[j] = row[threadIdx.x + j * 256];
    b[j] = mk[threadIdx.x + j * 256];
    if (!b[j].x) amax = fmaxf(amax, fabsf(v[j].x));
    if (!b[j].y) amax = fmaxf(amax, fabsf(v[j].y));
    if (!b[j].z) amax = fmaxf(amax, fabsf(v[j].z));
    if (!b[j].w) amax = fmaxf(amax, fabsf(v[j].w));
  }
  float mx = wave_block_max(amax, red);
  float s = fmaxf(mx * (1.0f / 127.0f), 1e-8f);
  if (threadIdx.x == 0) xs[m] = s;
  float iv = 1.0f / s;
  bf16_t* orow = Aq + (size_t)m * K_DIM;
  #pragma unroll
  for (int j = 0; j < 4; j++) {
    float f0 = v[j].x * iv, f1 = v[j].y * iv, f2 = v[j].z * iv, f3 = v[j].w * iv;
    bf16x4 q;
    q[0] = (bf16_t)(b[j].x ? f0 : rintf(f0));
    q[1] = (bf16_t)(b[j].y ? f1 : rintf(f1));
    q[2] = (bf16_t)(b[j].z ? f2 : rintf(f2));
    q[3] = (bf16_t)(b[j].w ? f3 : rintf(f3));
    *(bf16x4*)(orow + (size_t)(threadIdx.x + j * 256) * 4) = q;
  }
}

// ---------------- GEMM: 256x256, 8 waves, 4-slot ring, reg-pipelined 2-phase ----
// out[m,n] = xs[m]*sc[n] * sum_k A[m,k]*B[n,k]
//
// LDS slot s (32 KiB): A[256][32] at s*16384 elems, B[256][32] at +8192.
// Swizzle: (row,k) at byte row*64 + ((k>>3)^((row>>1)&3))*16 + (k&7)*2
// (conflict-free, verified R1/R2: SQ_LDS_BANK_CONFLICT == 0). global_load_lds
// dest linear, global SOURCE column pre-swizzled with the same involution.
//
// Schedule v3 (reg double-buffer, counted waits, 2 barriers/tile):
//   phase1(t): issue afB(t)[4]; stageA(t+3); lgkmcnt(4) [waits afA/bfr(t) only];
//              MFMA cluster A (16)  <- afB(t) completes under it
//   phase2(t): vmcnt(6)+barrier [tile t+1 landed, 3 stage-pairs in flight];
//              issue afA/bfr(t+1)[8] into alt reg set; stageB(t+3);
//              lgkmcnt(8) [waits afB(t) only]; MFMA cluster B (16)
//              <- next tile's reads complete under it
// WAR safety: writes to slot t-1 (stage t+3) are >=1 barrier after every
// wave's last read-drain of that slot. Loop unrolled x2 for static register
// renaming; serial 4-tile tail with vmcnt ladder 8/4/0.

__global__ __launch_bounds__(512, 2) void gemm_kernel(
    const bf16_t* __restrict__ A, const bf16_t* __restrict__ B,
    const float* __restrict__ xs, const float* __restrict__ sc,
    float* __restrict__ out, int M, int N) {
  __shared__ __align__(16) bf16_t lds[4 * 16384];  // 128 KiB

  const int tid  = threadIdx.x;
  const int lane = tid & 63;
  const int wave = tid >> 6;               // 0..7
  const int wmBase = (wave >> 2) * 128;    // wave's M offset
  const int wnBase = (wave & 3) * 64;      // wave's N offset
  const int l15  = lane & 15;
  const int quad = lane >> 4;
  const int swz8 = (quad ^ ((l15 >> 1) & 3)) * 8;  // swizzled k-slot, elems

  // XCD-aware bijective tile mapping: nwg = 32*43 = 1376 (%8==0).
  const int ntn = N / BN;
  const int nwg = (M / BM) * ntn;
  int bid = blockIdx.x;
  int lid = (bid & 7) * (nwg >> 3) + (bid >> 3);
  const int g4 = ntn * 4;
  const int tm = (lid / g4) * 4 + (lid & 3);
  const int tn = (lid % g4) >> 2;
  const int bm = tm * BM;
  const int bn = tn * BN;

  // staging: stored slot = lane&3; logical k-slot = (lane&3)^((lane>>3)&3)
  const int srow = wave * 16 + (lane >> 2);
  const int scol = ((lane & 3) ^ ((lane >> 3) & 3)) * 8;
  const bf16_t* gA = A + (size_t)(bm + srow) * K_DIM + scol;
  const bf16_t* gB = B + (size_t)(bn + srow) * K_DIM + scol;
  bf16_t* ldsA = lds + wave * 512;
  bf16_t* ldsB = lds + 8192 + wave * 512;

  auto stageA = [&](int t) {
    const bf16_t* g = gA + (size_t)t * BK;
    bf16_t* d = ldsA + (t & 3) * 16384;
    async16(g, d);
    async16(g + (size_t)128 * K_DIM, d + 4096);
  };
  auto stageB = [&](int t) {
    const bf16_t* g = gB + (size_t)t * BK;
    bf16_t* d = ldsB + (t & 3) * 16384;
    async16(g, d);
    async16(g + (size_t)128 * K_DIM, d + 4096);
  };

  f32x4 acc[8][4];
  #pragma unroll
  for (int i = 0; i < 8; ++i)
    #pragma unroll
    for (int j = 0; j < 4; ++j)
      #pragma unroll
      for (int e = 0; e < 4; ++e) acc[i][j][e] = 0.f;

  bf16x8 afA_p[4], bfr_p[4], afA_q[4], bfr_q[4], afB[4];

  // prologue: tiles 0,1,2 in flight (12 loads); land tile 0; preload frags(0)
  stageA(0); stageB(0); stageA(1); stageB(1); stageA(2); stageB(2);
  asm volatile("s_waitcnt vmcnt(8)" ::: "memory");
  __builtin_amdgcn_s_barrier();
  {
    const bf16_t* Asl = lds;
    const bf16_t* Bsl = lds + 8192;
    #pragma unroll
    for (int i = 0; i < 4; ++i)
      afA_p[i] = *(const bf16x8*)(Asl + (wmBase + i * 16 + l15) * 32 + swz8);
    #pragma unroll
    for (int j = 0; j < 4; ++j)
      bfr_p[j] = *(const bf16x8*)(Bsl + (wnBase + j * 16 + l15) * 32 + swz8);
  }

#define HALF_TILE(U, AF_CUR, BF_CUR, AF_NXT, BF_NXT)                           \
  {                                                                            \
    const int u_ = (U);                                                        \
    const bf16_t* Asl = lds + (u_ & 3) * 16384;                                \
    const bf16_t* Nsl = lds + ((u_ + 1) & 3) * 16384;                          \
    /* ---- phase 1 ---- */                                                    \
    __builtin_amdgcn_s_barrier();                                              \
    _Pragma("unroll")                                                          \
    for (int i = 0; i < 4; ++i)                                                \
      afB[i] = *(const bf16x8*)(Asl + (wmBase + 64 + i * 16 + l15) * 32 + swz8);\
    stageA(u_ + 3);                                                            \
    asm volatile("s_waitcnt lgkmcnt(4)" ::: "memory");                         \
    __builtin_amdgcn_sched_barrier(0);                                         \
    __builtin_amdgcn_s_setprio(1);                                             \
    _Pragma("unroll")                                                          \
    for (int i = 0; i < 4; ++i)                                                \
      _Pragma("unroll")                                                        \
      for (int j = 0; j < 4; ++j)                                              \
        acc[i][j] = __builtin_amdgcn_mfma_f32_16x16x32_bf16(                   \
            AF_CUR[i], BF_CUR[j], acc[i][j], 0, 0, 0);                         \
    __builtin_amdgcn_s_setprio(0);                                             \
    __builtin_amdgcn_sched_barrier(0);                                         \
    /* ---- phase 2: checkpoint + next-tile prefetch ---- */                   \
    asm volatile("s_waitcnt vmcnt(6)" ::: "memory");                           \
    __builtin_amdgcn_s_barrier();                                              \
    _Pragma("unroll")                                                          \
    for (int i = 0; i < 4; ++i)                                                \
      AF_NXT[i] = *(const bf16x8*)(Nsl + (wmBase + i * 16 + l15) * 32 + swz8); \
    _Pragma("unroll")                                                          \
    for (int j = 0; j < 4; ++j)                                                \
      BF_NXT[j] = *(const bf16x8*)(Nsl + 8192 + (wnBase + j * 16 + l15) * 32 + swz8);\
    stageB(u_ + 3);                                                            \
    asm volatile("s_waitcnt lgkmcnt(8)" ::: "memory");                         \
    __builtin_amdgcn_sched_barrier(0);                                         \
    __builtin_amdgcn_s_setprio(1);                                             \
    _Pragma("unroll")                                                          \
    for (int i = 0; i < 4; ++i)                                                \
      _Pragma("unroll")                                                        \
      for (int j = 0; j < 4; ++j)                                              \
        acc[4 + i][j] = __builtin_amdgcn_mfma_f32_16x16x32_bf16(               \
            afB[i], BF_CUR[j], acc[4 + i][j], 0, 0, 0);                        \
    __builtin_amdgcn_s_setprio(0);                                             \
    __builtin_amdgcn_sched_barrier(0);                                         \
  }

  // main loop: tiles 0..NT-5 (pairs), all stage targets < NT, steady vmcnt(6)
  for (int t = 0; t + 5 < NT; t += 2) {
    HALF_TILE(t,     afA_p, bfr_p, afA_q, bfr_q);
    HALF_TILE(t + 1, afA_q, bfr_q, afA_p, bfr_p);
  }

  // tail: tiles NT-4..NT-1, serial R2-style with vmcnt ladder 8/4/0
  for (int u = NT - 4; u < NT; ++u) {
    const bf16_t* Asl = lds + (u & 3) * 16384;
    const bf16_t* Bsl = Asl + 8192;
    __builtin_amdgcn_s_barrier();
    bf16x8 a0[4], b0[4], a1[4];
    #pragma unroll
    for (int i = 0; i < 4; ++i)
      a0[i] = *(const bf16x8*)(Asl + (wmBase + i * 16 + l15) * 32 + swz8);
    #pragma unroll
    for (int j = 0; j < 4; ++j)
      b0[j] = *(const bf16x8*)(Bsl + (wnBase + j * 16 + l15) * 32 + swz8);
    #pragma unroll
    for (int i = 0; i < 4; ++i)
      a1[i] = *(const bf16x8*)(Asl + (wmBase + 64 + i * 16 + l15) * 32 + swz8);
    if (u + 3 < NT) { stageA(u + 3); stageB(u + 3); }
    asm volatile("s_waitcnt lgkmcnt(0)" ::: "memory");
    __builtin_amdgcn_sched_barrier(0);
    __builtin_amdgcn_s_setprio(1);
    #pragma unroll
    for (int i = 0; i < 4; ++i)
      #pragma unroll
      for (int j = 0; j < 4; ++j)
        acc[i][j] = __builtin_amdgcn_mfma_f32_16x16x32_bf16(a0[i], b0[j],
                                                            acc[i][j], 0, 0, 0);
    #pragma unroll
    for (int i = 0; i < 4; ++i)
      #pragma unroll
      for (int j = 0; j < 4; ++j)
        acc[4 + i][j] = __builtin_amdgcn_mfma_f32_16x16x32_bf16(a1[i], b0[j],
                                                                acc[4 + i][j], 0, 0, 0);
    __builtin_amdgcn_s_setprio(0);
    __builtin_amdgcn_sched_barrier(0);
    if (u + 1 < NT) {
      int rem = NT - 1 - u;
      if (rem >= 3)      asm volatile("s_waitcnt vmcnt(8)" ::: "memory");
      else if (rem == 2) asm volatile("s_waitcnt vmcnt(4)" ::: "memory");
      else               asm volatile("s_waitcnt vmcnt(0)" ::: "memory");
    }
  }
#undef HALF_TILE

  // epilogue: C/D layout col=lane&15, row=quad*4+reg
  float scv[4];
  #pragma unroll
  for (int tj = 0; tj < 4; ++tj) scv[tj] = sc[bn + wnBase + tj * 16 + l15];
  #pragma unroll
  for (int mi = 0; mi < 8; ++mi) {
    #pragma unroll
    for (int i = 0; i < 4; ++i) {
      int row = bm + wmBase + mi * 16 + quad * 4 + i;
      float s_row = xs[row];
      float* orow = out + (size_t)row * N + bn + wnBase + l15;
      #pragma unroll
      for (int tj = 0; tj < 4; ++tj)
        orow[tj * 16] = acc[mi][tj][i] * s_row * scv[tj];
    }
  }
}

// ---------------- launch ----------------

extern "C" void kernel_launch(void* const* d_in, const int* in_sizes, int n_in,
                              void* d_out, int out_size, void* d_ws, size_t ws_size,
                              hipStream_t stream) {
  const float* x = (const float*)d_in[0];
  const float* W = (const float*)d_in[1];
  const float* sigma = (const float*)d_in[2];
  float* out = (float*)d_out;

  const int K = K_DIM;
  const int M = in_sizes[0] / K;  // 8192
  const int N = in_sizes[1] / K;  // 11008

  char* ws = (char*)d_ws;
  size_t off = 0;
  auto alloc = [&](size_t bytes) -> void* {
    void* p = ws + off;
    off += (bytes + 255) & ~(size_t)255;
    return p;
  };
  float* scale_col = (float*)alloc((size_t)N * 4);
  int*   mask      = (int*)alloc((size_t)K * 4);
  float* xs        = (float*)alloc((size_t)M * 4);
  bf16_t* Wq       = (bf16_t*)alloc((size_t)N * K * 2);
  bf16_t* Aq       = (bf16_t*)alloc((size_t)M * K * 2);

  hipMemsetAsync(mask, 0, (size_t)K * sizeof(int), stream);

  long total4 = (long)M * K / 4;
  colmask_kernel<<<4096, 256, 0, stream>>>(x, sigma, mask, total4);

  fused_w_kernel<<<N, 256, 0, stream>>>(W, scale_col, Wq);
  fused_x_kernel<<<M, 256, 0, stream>>>(x, mask, xs, Aq);

  dim3 grid((M / BM) * (N / BN));  // 1376 blocks, XCD-swizzled in-kernel
  gemm_kernel<<<grid, 512, 0, stream>>>(Aq, Wq, xs, scale_col, out, M, N);
}